// Round 11
// baseline (932.071 us; speedup 1.0000x reference)
//
#include <hip/hip_runtime.h>
#include <hip/hip_bf16.h>
#include <math.h>

// ---------------------------------------------------------------------------
// Block_38543036514772 on MI355X (gfx950). f32 in/out; bf16 MFMA internals.
// R17 (base R16 = 929us): (1) T5 setprio(1) around flash QK/PV MFMA clusters
// (independent blocks at ~2.5/CU = the m191 attn regime, not m190 lockstep).
// (2) T13 defer-max rescale in flash (THR=8, exp2 domain, wave-uniform
// branch): skips alpha shfl-gather + 16 acc mults most iters. (3) addpos_k
// and t2s_prep_q fused into s2t_kv / t2s_q GEMMs via f32-A reg-staging
// (AF template path: float4 + pos add + bf16x4 ds_write; removes two serial
// 29MB elementwise passes). GEMM structure otherwise unchanged (XCD swizzle
// kept: neutral, not harmful).
// ---------------------------------------------------------------------------

typedef __bf16 bf16_t;
typedef bf16_t bf16x4 __attribute__((ext_vector_type(4)));
typedef bf16_t bf16x8 __attribute__((ext_vector_type(8)));
typedef float  f32x4  __attribute__((ext_vector_type(4)));

typedef const __attribute__((address_space(1))) void* gas_t;
typedef __attribute__((address_space(3))) void* las_t;
__device__ __forceinline__ void async16(const void* g, void* l) {
    // LDS dest = wave-uniform base + lane*16 (no padding allowed!)
    __builtin_amdgcn_global_load_lds((gas_t)g, (las_t)l, 16, 0, 0);
}

#define MFMA(a,b,c) __builtin_amdgcn_mfma_f32_16x16x32_bf16((a),(b),(c),0,0,0)
#define EXP2(x) __builtin_amdgcn_exp2f(x)
#define LOG2E 1.4426950408889634f

// Bijective XCD chunking (m204): physical bid -> logical id such that each
// XCD (bid%8) owns a contiguous logical chunk. Valid for any nwg.
__device__ __forceinline__ int xcd_swz(int bid, int nwg) {
    const int q = nwg >> 3, r = nwg & 7, x = bid & 7, o = bid >> 3;
    return (x < r ? x * (q + 1) : r * (q + 1) + (x - r) * q) + o;
}

// ---------------------------------------------------------------------------
// Big GEMM 128x128: Y = act(A[M,K]bf16 * W[N,K]bf16^T + bias) (+res1)(+s*res2)
// AF=0: A bf16 via async16. AF=1: A = f32 af_src[row] + af_pos[row%196]
// (fused addpos). Staged by 256 threads as 8 float4 chunks -> bf16x4 writes.
// ---------------------------------------------------------------------------
template<bool GELU, int AF>
__global__ __launch_bounds__(256) void gemm128(
    const bf16_t* __restrict__ A, const bf16_t* __restrict__ W,
    const float* __restrict__ bias,
    const float* __restrict__ res1, const float* __restrict__ res2,
    float res2_scale,
    float* __restrict__ Yf, bf16_t* __restrict__ Yb,
    int M, int N, int K,
    const float* __restrict__ af_src, const float* __restrict__ af_pos)
{
    __shared__ bf16_t As[128*64];
    __shared__ bf16_t Bs[128*64];
    const int tid = threadIdx.x, wave = tid >> 6, lane = tid & 63;
    const int nbx = N >> 7;
    const int lb = xcd_swz(blockIdx.x, gridDim.x);
    const int m0 = (lb / nbx) * 128, n0 = (lb % nbx) * 128;
    const int wm = (wave & 1) * 64, wn = (wave >> 1) * 64;
    const int l15 = lane & 15, lq = lane >> 4;
    const int lrow = lane >> 3, lcol = (lane & 7) * 8;

    f32x4 acc[4][4] = {};

    for (int k0 = 0; k0 < K; k0 += 64) {
#pragma unroll
        for (int c = 0; c < 4; ++c) {
            const int r = wave * 32 + c * 8;
            if (AF == 0)
                async16(A + (size_t)(m0 + r + lrow) * K + k0 + lcol, &As[r * 64]);
            async16(W + (size_t)(n0 + r + lrow) * K + k0 + lcol, &Bs[r * 64]);
        }
        if (AF == 1) {
#pragma unroll
            for (int j = 0; j < 8; ++j) {
                const int ch = tid + j * 256;          // 0..2047
                const int r = ch >> 4, c4 = (ch & 15) * 4;
                const int gm = m0 + r;
                const int prow = gm % 196;
                const float4 xv = *(const float4*)(af_src + (size_t)gm * K + k0 + c4);
                const float4 pv = *(const float4*)(af_pos + (size_t)prow * 768 + k0 + c4);
                bf16x4 p;
                p[0] = (bf16_t)(xv.x + pv.x); p[1] = (bf16_t)(xv.y + pv.y);
                p[2] = (bf16_t)(xv.z + pv.z); p[3] = (bf16_t)(xv.w + pv.w);
                *(bf16x4*)&As[r * 64 + c4] = p;
            }
        }
        __syncthreads();
#pragma unroll
        for (int kk = 0; kk < 64; kk += 32) {
            bf16x8 a[4], b[4];
#pragma unroll
            for (int i = 0; i < 4; ++i)
                a[i] = *(const bf16x8*)&As[(wm + i * 16 + l15) * 64 + kk + lq * 8];
#pragma unroll
            for (int i = 0; i < 4; ++i)
                b[i] = *(const bf16x8*)&Bs[(wn + i * 16 + l15) * 64 + kk + lq * 8];
#pragma unroll
            for (int mi = 0; mi < 4; ++mi)
#pragma unroll
                for (int ni = 0; ni < 4; ++ni)
                    acc[mi][ni] = MFMA(a[mi], b[ni], acc[mi][ni]);
        }
        __syncthreads();
    }

#pragma unroll
    for (int mi = 0; mi < 4; ++mi)
#pragma unroll
    for (int ni = 0; ni < 4; ++ni) {
        const int gn = n0 + wn + ni * 16 + l15;
        const float bv = bias ? bias[gn] : 0.f;
#pragma unroll
        for (int i = 0; i < 4; ++i) {
            const int gm = m0 + wm + mi * 16 + lq * 4 + i;
            float v = acc[mi][ni][i] + bv;
            if (GELU) v = 0.5f * v * (1.0f + erff(v * 0.70710678118654752f));
            const size_t off = (size_t)gm * N + gn;
            if (res1) v += res1[off];
            if (res2) v += res2_scale * res2[off];
            if (Yf) Yf[off] = v;
            if (Yb) Yb[off] = (bf16_t)v;
        }
    }
}

// ---------------------------------------------------------------------------
// GEMM 128x64 tile for N=768 layers. 1-D grid, XCD-swizzled.
// EPI=1: fused t2s_prep_kv write; EPI=2: fused s_out write.
// AF=2: A = f32 af_src with t2s_prep_q permutation + af_pos[t] (fused prep_q).
// ---------------------------------------------------------------------------
template<bool GELU, int EPI, int AF>
__global__ __launch_bounds__(256) void gemm128x64(
    const bf16_t* __restrict__ A, const bf16_t* __restrict__ W,
    const float* __restrict__ bias,
    const float* __restrict__ res1, const float* __restrict__ res2,
    float res2_scale,
    float* __restrict__ Yf, bf16_t* __restrict__ Yb,
    int M, int N, int K,
    const float* __restrict__ ep_a, float* __restrict__ ep_fo,
    bf16_t* __restrict__ ep_bo,
    const float* __restrict__ af_src, const float* __restrict__ af_pos)
{
    __shared__ bf16_t As[128*64];
    __shared__ bf16_t Bs[64*64];
    const int tid = threadIdx.x, wave = tid >> 6, lane = tid & 63;
    const int nbx = N >> 6;
    const int lb = xcd_swz(blockIdx.x, gridDim.x);
    const int m0 = (lb / nbx) * 128, n0 = (lb % nbx) * 64;
    const int wm = (wave & 1) * 64, wn = (wave >> 1) * 32;
    const int l15 = lane & 15, lq = lane >> 4;
    const int lrow = lane >> 3, lcol = (lane & 7) * 8;

    f32x4 acc[4][2] = {};

    for (int k0 = 0; k0 < K; k0 += 64) {
        if (AF == 0) {
#pragma unroll
            for (int c = 0; c < 4; ++c) {
                const int r = wave * 32 + c * 8;
                async16(A + (size_t)(m0 + r + lrow) * K + k0 + lcol, &As[r * 64]);
            }
        } else {
#pragma unroll
            for (int j = 0; j < 8; ++j) {
                const int ch = tid + j * 256;
                const int r = ch >> 4, c4 = (ch & 15) * 4;
                const int gm = m0 + r;
                // gm = (b*196+n)*8 + t  ->  src row (b*8+t)*196 + n
                const int t_ = gm & 7, bn = gm >> 3;
                const int n_ = bn % 196, b_ = bn / 196;
                const int srow = (b_ * 8 + t_) * 196 + n_;
                const float4 xv = *(const float4*)(af_src + (size_t)srow * K + k0 + c4);
                const float4 pv = *(const float4*)(af_pos + (size_t)t_ * 768 + k0 + c4);
                bf16x4 p;
                p[0] = (bf16_t)(xv.x + pv.x); p[1] = (bf16_t)(xv.y + pv.y);
                p[2] = (bf16_t)(xv.z + pv.z); p[3] = (bf16_t)(xv.w + pv.w);
                *(bf16x4*)&As[r * 64 + c4] = p;
            }
        }
#pragma unroll
        for (int c = 0; c < 2; ++c) {
            const int r = wave * 16 + c * 8;
            async16(W + (size_t)(n0 + r + lrow) * K + k0 + lcol, &Bs[r * 64]);
        }
        __syncthreads();
#pragma unroll
        for (int kk = 0; kk < 64; kk += 32) {
            bf16x8 a[4], b[2];
#pragma unroll
            for (int i = 0; i < 4; ++i)
                a[i] = *(const bf16x8*)&As[(wm + i * 16 + l15) * 64 + kk + lq * 8];
#pragma unroll
            for (int i = 0; i < 2; ++i)
                b[i] = *(const bf16x8*)&Bs[(wn + i * 16 + l15) * 64 + kk + lq * 8];
#pragma unroll
            for (int mi = 0; mi < 4; ++mi)
#pragma unroll
                for (int ni = 0; ni < 2; ++ni)
                    acc[mi][ni] = MFMA(a[mi], b[ni], acc[mi][ni]);
        }
        __syncthreads();
    }

#pragma unroll
    for (int mi = 0; mi < 4; ++mi)
#pragma unroll
    for (int ni = 0; ni < 2; ++ni) {
        const int gn = n0 + wn + ni * 16 + l15;
        const float bv = bias ? bias[gn] : 0.f;
#pragma unroll
        for (int i = 0; i < 4; ++i) {
            const int gm = m0 + wm + mi * 16 + lq * 4 + i;
            float v = acc[mi][ni][i] + bv;
            if (GELU) v = 0.5f * v * (1.0f + erff(v * 0.70710678118654752f));
            const size_t off = (size_t)gm * N + gn;
            if (res1) v += res1[off];
            if (res2) v += res2_scale * res2[off];
            if (Yf) Yf[off] = v;
            if (Yb) Yb[off] = (bf16_t)v;
            if (EPI == 1) {
                // gm = b*1568 + t*196 + n  ->  dest = (b*196+n)*8 + t
                const int b_ = gm / 1568, r_ = gm - b_ * 1568;
                const int t_ = r_ / 196,  n_ = r_ - t_ * 196;
                const int dest = ((b_ * 196 + n_) << 3) + t_;
                ep_bo[(size_t)dest * 768 + gn] =
                    (bf16_t)(v + ep_a[t_ * 768 + gn]);
            }
            if (EPI == 2) {
                // gm = (b*196+n)*8 + t  ->  dest = (b*8+t)*196 + n
                const int t_ = gm & 7, bn_ = gm >> 3;
                const int n_ = bn_ % 196, b_ = bn_ / 196;
                const int dest = (b_ * 8 + t_) * 196 + n_;
                const size_t doff = (size_t)dest * 768 + gn;
                ep_fo[doff] = ep_a[doff] + v;
            }
        }
    }
}

// ---------------------------------------------------------------------------
// Small GEMM (adapters, N or K = 192): f32 in, 64x64 tile. 1-D swizzled grid.
// EPI=1: also write ep_bo[off] = bf16(v + ep_pos[(gm%196)*768 + gn])
// ---------------------------------------------------------------------------
template<bool GELU, int EPI>
__global__ __launch_bounds__(256) void gemm_bt(
    const float* __restrict__ X, const float* __restrict__ W,
    const float* __restrict__ bias,
    const float* __restrict__ res1, const float* __restrict__ res2,
    float res2_scale,
    float* __restrict__ Y, int M, int N, int K,
    const float* __restrict__ ep_pos, bf16_t* __restrict__ ep_bo)
{
    __shared__ bf16_t As[64][72];
    __shared__ bf16_t Bs[64][72];
    const int tid  = threadIdx.x;
    const int nbx  = N >> 6;
    const int lb   = xcd_swz(blockIdx.x, gridDim.x);
    const int n0   = (lb % nbx) * 64;
    const int m0   = (lb / nbx) * 64;
    const int wave = tid >> 6, lane = tid & 63;
    const int wm   = (wave & 1) * 32, wn = (wave >> 1) * 32;
    const int l15  = lane & 15, lq = lane >> 4;
    f32x4 acc[2][2] = {};
    const int sr = tid >> 4;
    const int sc4 = (tid & 15) * 4;

    for (int k0 = 0; k0 < K; k0 += 64) {
#pragma unroll
        for (int i = 0; i < 4; ++i) {
            const int row = sr + i * 16;
            const float4 xv = *reinterpret_cast<const float4*>(
                X + (size_t)(m0 + row) * K + k0 + sc4);
            bf16x4 p;
            p[0] = (bf16_t)xv.x; p[1] = (bf16_t)xv.y;
            p[2] = (bf16_t)xv.z; p[3] = (bf16_t)xv.w;
            *reinterpret_cast<bf16x4*>(&As[row][sc4]) = p;
        }
#pragma unroll
        for (int i = 0; i < 4; ++i) {
            const int row = sr + i * 16;
            const float4 wv = *reinterpret_cast<const float4*>(
                W + (size_t)(n0 + row) * K + k0 + sc4);
            bf16x4 p;
            p[0] = (bf16_t)wv.x; p[1] = (bf16_t)wv.y;
            p[2] = (bf16_t)wv.z; p[3] = (bf16_t)wv.w;
            *reinterpret_cast<bf16x4*>(&Bs[row][sc4]) = p;
        }
        __syncthreads();
#pragma unroll
        for (int kk = 0; kk < 64; kk += 32) {
            bf16x8 a0 = *reinterpret_cast<const bf16x8*>(&As[wm +      l15][kk + lq * 8]);
            bf16x8 a1 = *reinterpret_cast<const bf16x8*>(&As[wm + 16 + l15][kk + lq * 8]);
            bf16x8 b0 = *reinterpret_cast<const bf16x8*>(&Bs[wn +      l15][kk + lq * 8]);
            bf16x8 b1 = *reinterpret_cast<const bf16x8*>(&Bs[wn + 16 + l15][kk + lq * 8]);
            acc[0][0] = MFMA(a0, b0, acc[0][0]);
            acc[0][1] = MFMA(a0, b1, acc[0][1]);
            acc[1][0] = MFMA(a1, b0, acc[1][0]);
            acc[1][1] = MFMA(a1, b1, acc[1][1]);
        }
        __syncthreads();
    }

#pragma unroll
    for (int mt = 0; mt < 2; ++mt)
#pragma unroll
    for (int nt = 0; nt < 2; ++nt) {
        const int gn = n0 + wn + nt * 16 + l15;
        const float bv = bias[gn];
#pragma unroll
        for (int i = 0; i < 4; ++i) {
            const int gm = m0 + wm + mt * 16 + lq * 4 + i;
            float v = acc[mt][nt][i] + bv;
            if (GELU) v = 0.5f * v * (1.0f + erff(v * 0.70710678118654752f));
            const size_t off = (size_t)gm * N + gn;
            if (res1) v += res1[off];
            if (res2) v += res2_scale * res2[off];
            Y[off] = v;
            if (EPI == 1) {
                const int n_ = gm % 196;
                ep_bo[off] = (bf16_t)(v + ep_pos[n_ * 768 + gn]);
            }
        }
    }
}

// ---------------------------------------------------------------------------
// Flash attention v9 (swapped QK^T): wave w owns Q rows [16w,16w+16).
// Q frags in REGISTERS. K staged row-major coalesced; V staged via row-loads
// + scalar transpose ds_writes. P^T packed b64 into own Ps buffer -> 2
// barriers/iter. R17: setprio(1) around QK/PV MFMA clusters (T5, independent
// blocks regime) + defer-max rescale (T13, THR=8 exp2-domain, wave-uniform).
// ---------------------------------------------------------------------------
__global__ __launch_bounds__(256) void flash_k(
    const bf16_t* __restrict__ Q, int ldq,
    const bf16_t* __restrict__ Kp, int ldk,
    const bf16_t* __restrict__ Vp, int ldv,
    bf16_t* __restrict__ O, int ldo,
    int nq, int nk, float scale)
{
    __shared__ bf16_t Ks[64 * 68];
    __shared__ bf16_t Vs[64 * 68];    // V^T: [dim][key]
    __shared__ bf16_t Ps[64 * 68];    // P: [q-row][key], wave-private rows

    const int tid = threadIdx.x, wave = tid >> 6, lane = tid & 63;
    const int q0 = blockIdx.x * 64, hoff = blockIdx.y * 64, g = blockIdx.z;
    const int l15 = lane & 15, lq = lane >> 4;
    const int wm16 = wave * 16;
    const int sr = tid >> 3, sc8 = (tid & 7) * 8;   // K staging: 32 rows x 8 chunks
    const float sl2e = scale * LOG2E;

    // ---- Q fragments in registers (loop-invariant) ----
    bf16x8 bq0, bq1;
    {
        int qr = q0 + wm16 + l15; if (qr > nq - 1) qr = nq - 1;
        const bf16_t* qp = Q + ((size_t)g * nq + qr) * ldq + hoff + lq * 8;
        bq0 = *(const bf16x8*)qp;
        bq1 = *(const bf16x8*)(qp + 32);
    }

    // ---- prologue: prefetch K/V tile 0 into regs (coalesced row loads) ----
    bf16x8 ka, kb, va, vb;
    {
        int r0 = sr;      if (r0 > nk - 1) r0 = nk - 1;
        int r1 = sr + 32; if (r1 > nk - 1) r1 = nk - 1;
        ka = *(const bf16x8*)(Kp + ((size_t)g * nk + r0) * ldk + hoff + sc8);
        kb = *(const bf16x8*)(Kp + ((size_t)g * nk + r1) * ldk + hoff + sc8);
        int key = lane; if (key > nk - 1) key = nk - 1;
        const bf16_t* vp = Vp + ((size_t)g * nk + key) * ldv + hoff + wm16;
        va = *(const bf16x8*)vp;
        vb = *(const bf16x8*)(vp + 8);
    }

    float m_r = -INFINITY, l_r = 0.f;   // softmax state for q-row = wm16 + l15
    f32x4 acc[4] = {};                  // O rows lq*4+i, cols nt*16+l15

    for (int kk0 = 0; kk0 < nk; kk0 += 64) {
        __syncthreads();   // prev-iter QK/PV reads of Ks/Vs done; prefetch ready
        // ---- regs -> LDS (K rows; V transposed via scalar stores) ----
        *(bf16x8*)&Ks[sr * 68 + sc8] = ka;
        *(bf16x8*)&Ks[(sr + 32) * 68 + sc8] = kb;
#pragma unroll
        for (int j = 0; j < 8; ++j) Vs[(wm16 + j) * 68 + lane] = va[j];
#pragma unroll
        for (int j = 0; j < 8; ++j) Vs[(wm16 + 8 + j) * 68 + lane] = vb[j];
        __syncthreads();   // staging visible

        // ---- issue NEXT tile's global loads (fly under compute) ----
        const int nx = kk0 + 64;
        if (nx < nk) {
            int r0 = nx + sr;      if (r0 > nk - 1) r0 = nk - 1;
            int r1 = nx + sr + 32; if (r1 > nk - 1) r1 = nk - 1;
            ka = *(const bf16x8*)(Kp + ((size_t)g * nk + r0) * ldk + hoff + sc8);
            kb = *(const bf16x8*)(Kp + ((size_t)g * nk + r1) * ldk + hoff + sc8);
            int key = nx + lane; if (key > nk - 1) key = nk - 1;
            const bf16_t* vp = Vp + ((size_t)g * nk + key) * ldv + hoff + wm16;
            va = *(const bf16x8*)vp;
            vb = *(const bf16x8*)(vp + 8);
        }

        // ---- S^T = K Q^T : s[nt] = S[k=kk0+nt*16+lq*4+i][q=wm16+l15] ----
        f32x4 s[4] = {};
        __builtin_amdgcn_s_setprio(1);
#pragma unroll
        for (int nt = 0; nt < 4; ++nt) {
            bf16x8 ak0 = *(const bf16x8*)&Ks[(nt * 16 + l15) * 68 + lq * 8];
            bf16x8 ak1 = *(const bf16x8*)&Ks[(nt * 16 + l15) * 68 + 32 + lq * 8];
            s[nt] = MFMA(ak0, bq0, s[nt]);
            s[nt] = MFMA(ak1, bq1, s[nt]);
        }
        __builtin_amdgcn_s_setprio(0);

        // ---- mask + scale (k index is lane-local) ----
#pragma unroll
        for (int nt = 0; nt < 4; ++nt)
#pragma unroll
        for (int i = 0; i < 4; ++i) {
            const bool valid = (kk0 + nt * 16 + lq * 4 + i) < nk;
            s[nt][i] = valid ? s[nt][i] * sl2e : -INFINITY;
        }

        // ---- row softmax: local 16-tree + 2 shfl; defer-max (THR=8) ----
        float t0 = fmaxf(fmaxf(s[0][0], s[0][1]), fmaxf(s[0][2], s[0][3]));
        float t1 = fmaxf(fmaxf(s[1][0], s[1][1]), fmaxf(s[1][2], s[1][3]));
        float t2 = fmaxf(fmaxf(s[2][0], s[2][1]), fmaxf(s[2][2], s[2][3]));
        float t3 = fmaxf(fmaxf(s[3][0], s[3][1]), fmaxf(s[3][2], s[3][3]));
        float t = fmaxf(fmaxf(t0, t1), fmaxf(t2, t3));
        t = fmaxf(t, __shfl_xor(t, 16));
        t = fmaxf(t, __shfl_xor(t, 32));
        if (!__all(t <= m_r + 8.f)) {          // rescale path (always at iter 0)
            const float mnew = fmaxf(m_r, t);  // finite: >=1 valid k per tile
            const float a = EXP2(m_r - mnew);
            float alq[4];
#pragma unroll
            for (int i = 0; i < 4; ++i) alq[i] = __shfl(a, lq * 4 + i);
            l_r *= a;
#pragma unroll
            for (int nt = 0; nt < 4; ++nt)
#pragma unroll
            for (int i = 0; i < 4; ++i)
                acc[nt][i] *= alq[i];
            m_r = mnew;
        }
        float ps = 0.f;
#pragma unroll
        for (int nt = 0; nt < 4; ++nt)
#pragma unroll
        for (int i = 0; i < 4; ++i) {
            const float e = EXP2(s[nt][i] - m_r);  // -inf -> 0; bounded by 2^8
            s[nt][i] = e; ps += e;
        }
        ps += __shfl_xor(ps, 16);
        ps += __shfl_xor(ps, 32);
        l_r += ps;

        // ---- P^T into Ps, packed b64 (own rows; same-wave order = safe) ----
#pragma unroll
        for (int nt = 0; nt < 4; ++nt) {
            bf16x4 pk;
            pk[0] = (bf16_t)s[nt][0]; pk[1] = (bf16_t)s[nt][1];
            pk[2] = (bf16_t)s[nt][2]; pk[3] = (bf16_t)s[nt][3];
            *(bf16x4*)&Ps[(wm16 + l15) * 68 + nt * 16 + lq * 4] = pk;
        }

        // ---- O += P*V ----
        __builtin_amdgcn_s_setprio(1);
#pragma unroll
        for (int kk = 0; kk < 64; kk += 32) {
            bf16x8 ap = *(const bf16x8*)&Ps[(wm16 + l15) * 68 + kk + lq * 8];
#pragma unroll
            for (int nt = 0; nt < 4; ++nt) {
                bf16x8 bv = *(const bf16x8*)&Vs[(nt * 16 + l15) * 68 + kk + lq * 8];
                acc[nt] = MFMA(ap, bv, acc[nt]);
            }
        }
        __builtin_amdgcn_s_setprio(0);
    }

    // ---- epilogue: 1/l gathered to acc rows ----
    float linv[4];
#pragma unroll
    for (int i = 0; i < 4; ++i)
        linv[i] = __builtin_amdgcn_rcpf(__shfl(l_r, lq * 4 + i));
#pragma unroll
    for (int nt = 0; nt < 4; ++nt)
#pragma unroll
    for (int i = 0; i < 4; ++i) {
        const int qrow = q0 + wm16 + lq * 4 + i;
        if (qrow < nq)
            O[((size_t)g * nq + qrow) * ldo + hoff + nt * 16 + l15] =
                (bf16_t)(acc[nt][i] * linv[i]);
    }
}

// ---------------------------------------------------------------------------
// T2S attention (nq=nk=8, D=64, 12 heads): ONE WAVE per (seq, head).
// ---------------------------------------------------------------------------
__global__ __launch_bounds__(256) void attn8_k(
    const bf16_t* __restrict__ Q, int ldq,
    const bf16_t* __restrict__ Kp, int ldk,
    const bf16_t* __restrict__ Vp, int ldv,
    bf16_t* __restrict__ O, int ldo,
    float scale)
{
    __shared__ float Ps[4][8][8];
    const int wv = threadIdx.x >> 6, lane = threadIdx.x & 63;
    const int gw  = blockIdx.x * 4 + wv;       // global wave id in [0, 9408)
    const int seq = gw / 12, h = gw - seq * 12;
    const int hoff = h * 64;
    const int l15 = lane & 15, lq = lane >> 4;
    const size_t rbase = (size_t)seq * 8;
    const float sl2e = scale * LOG2E;

    // ---- S = Q K^T : one 16x16 tile (8x8 valid) ----
    const int qr = l15 & 7;                     // rows/cols 8..15 duplicate 0..7
    const bf16_t* qp = Q  + (rbase + qr) * ldq + hoff + lq * 8;
    const bf16_t* kp = Kp + (rbase + qr) * ldk + hoff + lq * 8;
    bf16x8 a0 = *(const bf16x8*)qp;
    bf16x8 a1 = *(const bf16x8*)(qp + 32);
    bf16x8 b0 = *(const bf16x8*)kp;
    bf16x8 b1 = *(const bf16x8*)(kp + 32);
    f32x4 z = {};
    f32x4 s = MFMA(a1, b1, MFMA(a0, b0, z));
    // C layout: col(key) = l15, row(query) = lq*4+i — rows valid iff lq<2.

    // ---- softmax over 8 keys per row (cols 8..15 masked) ----
    const bool cvalid = l15 < 8;
    float p[4];
#pragma unroll
    for (int i = 0; i < 4; ++i) {
        float v = cvalid ? s[i] * sl2e : -INFINITY;
        float m = v;
        m = fmaxf(m, __shfl_xor(m, 1));
        m = fmaxf(m, __shfl_xor(m, 2));
        m = fmaxf(m, __shfl_xor(m, 4));
        m = fmaxf(m, __shfl_xor(m, 8));
        float e = EXP2(v - m);                  // -inf -> 0
        float sum = e;
        sum += __shfl_xor(sum, 1);
        sum += __shfl_xor(sum, 2);
        sum += __shfl_xor(sum, 4);
        sum += __shfl_xor(sum, 8);
        p[i] = e * __builtin_amdgcn_rcpf(sum);  // sum >= 1 (row max contributes 1)
    }
    if (lq < 2 && cvalid) {
#pragma unroll
        for (int i = 0; i < 4; ++i)
            Ps[wv][lq * 4 + i][l15] = p[i];
    }
    __syncthreads();

    // ---- O[qi][dg*8..+8) = sum_k P[qi][k] * V[k][...] ----
    const int qi = lane >> 3, dg = lane & 7;
    f32x4 p0 = *(const f32x4*)&Ps[wv][qi][0];
    f32x4 p1 = *(const f32x4*)&Ps[wv][qi][4];
    float acc[8] = {};
#pragma unroll
    for (int k = 0; k < 8; ++k) {
        const bf16x8 vvec = *(const bf16x8*)(Vp + (rbase + k) * ldv + hoff + dg * 8);
        const float pk = (k < 4) ? p0[k] : p1[k - 4];
#pragma unroll
        for (int j = 0; j < 8; ++j) acc[j] += pk * (float)vvec[j];
    }
    bf16x8 o;
#pragma unroll
    for (int j = 0; j < 8; ++j) o[j] = (bf16_t)acc[j];
    *(bf16x8*)(O + (rbase + qi) * ldo + hoff + dg * 8) = o;
}

// ---------------------------------------------------------------------------
// LayerNorm(768): bf16 out always, f32 out optional. Shfl reduce, 1 barrier.
// ---------------------------------------------------------------------------
__global__ __launch_bounds__(256) void ln_k(
    const float* __restrict__ x,
    const float* __restrict__ g, const float* __restrict__ bta,
    float* __restrict__ yf, bf16_t* __restrict__ yb)
{
    __shared__ float rA[4], rB[4];
    const int row = blockIdx.x, tid = threadIdx.x;
    const int wv = tid >> 6, lane = tid & 63;
    const size_t base = (size_t)row * 768;
    const float v0 = x[base + tid];
    const float v1 = x[base + tid + 256];
    const float v2 = x[base + tid + 512];
    float s1 = v0 + v1 + v2;
    float s2 = v0 * v0 + v1 * v1 + v2 * v2;
#pragma unroll
    for (int off = 32; off > 0; off >>= 1) {
        s1 += __shfl_xor(s1, off);
        s2 += __shfl_xor(s2, off);
    }
    if (lane == 0) { rA[wv] = s1; rB[wv] = s2; }
    __syncthreads();
    const float ts1 = rA[0] + rA[1] + rA[2] + rA[3];
    const float ts2 = rB[0] + rB[1] + rB[2] + rB[3];
    const float m = ts1 * (1.f / 768.f);
    const float r = rsqrtf(ts2 * (1.f / 768.f) - m * m + 1e-5f);
    const float o0 = (v0 - m) * r * g[tid]       + bta[tid];
    const float o1 = (v1 - m) * r * g[tid + 256] + bta[tid + 256];
    const float o2 = (v2 - m) * r * g[tid + 512] + bta[tid + 512];
    yb[base + tid]       = (bf16_t)o0;
    yb[base + tid + 256] = (bf16_t)o1;
    yb[base + tid + 512] = (bf16_t)o2;
    if (yf) {
        yf[base + tid]       = o0;
        yf[base + tid + 256] = o1;
        yf[base + tid + 512] = o2;
    }
}

// --------------------------- elementwise helpers ---------------------------
__global__ void build_qkv_bias(const float* __restrict__ qb,
                               const float* __restrict__ vb,
                               float* __restrict__ dst) {
    int i = blockIdx.x * 256 + threadIdx.x;
    if (i < 768) dst[i] = qb[i];
    else if (i < 1536) dst[i] = 0.f;
    else if (i < 2304) dst[i] = vb[i - 1536];
}

// Weight convert: 10 f32 weights -> one bf16 arena (float4 granularity).
// cum[i] = OFF_i / 4.
struct WPtrs { const float* p[10]; };
__global__ void wcvt(WPtrs s, bf16_t* __restrict__ dst) {
    const int cum[11] = {0, 442368, 589824, 737280, 1032192, 1179648,
                         1327104, 1622016, 1769472, 2359296, 2949120};
    const int gi = blockIdx.x * 256 + threadIdx.x;
    int seg = 0;
#pragma unroll
    for (int i = 1; i < 10; ++i) if (gi >= cum[i]) seg = i;
    const float4 v = ((const float4*)s.p[seg])[gi - cum[seg]];
    bf16x4 o;
    o[0] = (bf16_t)v.x; o[1] = (bf16_t)v.y; o[2] = (bf16_t)v.z; o[3] = (bf16_t)v.w;
    ((bf16x4*)dst)[gi] = o;
}

// Arena offsets (elements)
#define OFF_QKV    0
#define OFF_APROJ  1769472
#define OFF_S2TQ   2359296
#define OFF_S2TKV  2949120
#define OFF_S2TP   4128768
#define OFF_T2SQ   4718592
#define OFF_T2SKV  5308416
#define OFF_T2SP   6488064
#define OFF_FC1    7077888
#define OFF_FC2    9437184
#define W_TOTAL    11796480

// ---------------------------------------------------------------------------
extern "C" void kernel_launch(void* const* d_in, const int* in_sizes, int n_in,
                              void* d_out, int out_size, void* d_ws, size_t ws_size,
                              hipStream_t stream)
{
    typedef const float* fp;
    fp s_x     = (fp)d_in[0];
    fp t_x     = (fp)d_in[1];
    fp g1      = (fp)d_in[2];
    fp bb1     = (fp)d_in[3];
    fp qkv_w   = (fp)d_in[4];
    fp q_bias  = (fp)d_in[5];
    fp v_bias  = (fp)d_in[6];
    fp aproj_w = (fp)d_in[7];
    fp aproj_b = (fp)d_in[8];
    fp sa_w1   = (fp)d_in[9];
    fp sa_b1   = (fp)d_in[10];
    fp sa_w2   = (fp)d_in[11];
    fp sa_b2   = (fp)d_in[12];
    fp s2t_pos_cnn  = (fp)d_in[13];
    fp s2t_pos_vmae = (fp)d_in[14];
    fp s2t_qw  = (fp)d_in[15];
    fp s2t_qb  = (fp)d_in[16];
    fp s2t_kvw = (fp)d_in[17];
    fp s2t_kvb = (fp)d_in[18];
    fp s2t_pw  = (fp)d_in[19];
    fp s2t_pb  = (fp)d_in[20];
    fp t2s_pos_cnn  = (fp)d_in[21];
    fp t2s_pos_vmae = (fp)d_in[22];
    fp t2s_qw  = (fp)d_in[23];
    fp t2s_qb  = (fp)d_in[24];
    fp t2s_kvw = (fp)d_in[25];
    fp t2s_kvb = (fp)d_in[26];
    fp t2s_pw  = (fp)d_in[27];
    fp t2s_pb  = (fp)d_in[28];
    fp g2      = (fp)d_in[29];
    fp bb2     = (fp)d_in[30];
    fp fc1_w   = (fp)d_in[31];
    fp fc1_b   = (fp)d_in[32];
    fp fc2_w   = (fp)d_in[33];
    fp fc2_b   = (fp)d_in[34];
    fp ma_w1   = (fp)d_in[35];
    fp ma_b1   = (fp)d_in[36];
    fp ma_w2   = (fp)d_in[37];
    fp ma_b2   = (fp)d_in[38];

    const size_t RD = (size_t)6272 * 768;

    float* ws   = (float*)d_ws;
    float* F    = ws;                      // aproj out / mad out
    float* G    = F + RD;                  // running t
    float* CI   = G + RD;                  // ln2 f32 out (stage 4 only)
    float* Hb   = CI + RD;                 // 6272x192 adapter hidden
    float* qkvb = Hb + (size_t)6272 * 192;
    bf16_t* BW  = (bf16_t*)(qkvb + 2304);  // weight arena
    bf16_t* Xb  = BW + W_TOTAL;            // GEMM A-input staging (RD)
    bf16_t* Eb  = Xb + RD;                 // q mirrors / flash out (RD)
    bf16_t* Fb  = Eb + RD;                 // flash/attn out (RD)
    bf16_t* MB  = Fb + RD;                 // big mirror: qkv/kv/fc1 (6272x3072)
    bf16_t* Xkv = MB + (size_t)6272 * 1536; // fused t2s-kv staging (MB 2nd half)

    float* out_s = (float*)d_out;          // [32*196, 768]
    float* out_t = out_s + RD;             // [4*1568, 768]

    const dim3 blk(256);

    // ---- weight conversion ----
    WPtrs wp;
    wp.p[0] = qkv_w;  wp.p[1] = aproj_w; wp.p[2] = s2t_qw; wp.p[3] = s2t_kvw;
    wp.p[4] = s2t_pw; wp.p[5] = t2s_qw;  wp.p[6] = t2s_kvw; wp.p[7] = t2s_pw;
    wp.p[8] = fc1_w;  wp.p[9] = fc2_w;
    wcvt<<<11520, blk, 0, stream>>>(wp, BW);

    // ---- stage 1: self-attention + serial adapter ----
    ln_k<<<6272, blk, 0, stream>>>(t_x, g1, bb1, nullptr, Xb);
    build_qkv_bias<<<9, blk, 0, stream>>>(q_bias, v_bias, qkvb);
    gemm128<false, 0><<<dim3(18 * 49), blk, 0, stream>>>(
        Xb, BW + OFF_QKV, qkvb, nullptr, nullptr, 0.f, nullptr, MB, 6272, 2304, 768,
        nullptr, nullptr);
    flash_k<<<dim3(25, 12, 4), blk, 0, stream>>>(
        MB, 2304, MB + 768, 2304, MB + 1536, 2304, Eb, 768, 1568, 1568, 0.125f);
    gemm128x64<false, 0, 0><<<dim3(12 * 49), blk, 0, stream>>>(
        Eb, BW + OFF_APROJ, aproj_b, nullptr, nullptr, 0.f, F, nullptr, 6272, 768, 768,
        nullptr, nullptr, nullptr, nullptr, nullptr);
    gemm_bt<true, 0><<<dim3(3 * 98), blk, 0, stream>>>(
        F, sa_w1, sa_b1, nullptr, nullptr, 0.f, Hb, 6272, 192, 768, nullptr, nullptr);
    // t1 = G; fused: Xb = bf16(t1 + s2t_pos_vmae[n])
    gemm_bt<false, 1><<<dim3(12 * 98), blk, 0, stream>>>(
        Hb, sa_w2, sa_b2, F, t_x, 1.0f, G, 6272, 768, 192, s2t_pos_vmae, Xb);

    // ---- stage 2: S2T cross-attn ----
    gemm128x64<false, 0, 0><<<dim3(12 * 49), blk, 0, stream>>>(
        Xb, BW + OFF_S2TQ, s2t_qb, nullptr, nullptr, 0.f, nullptr, Eb, 6272, 768, 768,
        nullptr, nullptr, nullptr, nullptr, nullptr);
    // fused addpos: A = bf16(s_x + s2t_pos_cnn[row%196]) staged in-kernel
    gemm128<false, 1><<<dim3(12 * 49), blk, 0, stream>>>(
        nullptr, BW + OFF_S2TKV, s2t_kvb, nullptr, nullptr, 0.f, nullptr, MB,
        6272, 1536, 768, s_x, s2t_pos_cnn);
    flash_k<<<dim3(4, 12, 32), blk, 0, stream>>>(
        Eb, 768, MB, 1536, MB + 768, 1536, Fb, 768, 196, 196, 0.125f);
    // t2 = G; fused: Xkv[perm] = bf16(t2 + t2s_pos_vmae[t])
    gemm128x64<false, 1, 0><<<dim3(12 * 49), blk, 0, stream>>>(
        Fb, BW + OFF_S2TP, s2t_pb, G, nullptr, 0.f, G, nullptr, 6272, 768, 768,
        t2s_pos_vmae, nullptr, Xkv, nullptr, nullptr);

    // ---- stage 3: T2S cross-attn ----
    // fused t2s_prep_q: A = bf16(s_x[perm] + t2s_pos_cnn[t]) staged in-kernel
    gemm128x64<false, 0, 2><<<dim3(12 * 49), blk, 0, stream>>>(
        nullptr, BW + OFF_T2SQ, t2s_qb, nullptr, nullptr, 0.f, nullptr, Eb,
        6272, 768, 768, nullptr, nullptr, nullptr, s_x, t2s_pos_cnn);
    gemm128<false, 0><<<dim3(12 * 49), blk, 0, stream>>>(
        Xkv, BW + OFF_T2SKV, t2s_kvb, nullptr, nullptr, 0.f, nullptr, MB,
        6272, 1536, 768, nullptr, nullptr);
    attn8_k<<<dim3(2352), blk, 0, stream>>>(
        Eb, 768, MB, 1536, MB + 768, 1536, Fb, 768, 0.125f);
    // fused s_out: out_s[perm] = s_x[perm] + t2s_p(Fb)
    gemm128x64<false, 2, 0><<<dim3(12 * 49), blk, 0, stream>>>(
        Fb, BW + OFF_T2SP, t2s_pb, nullptr, nullptr, 0.f, nullptr, nullptr,
        6272, 768, 768, s_x, out_s, nullptr, nullptr, nullptr);

    // ---- stage 4: MLP + parallel adapter ----
    ln_k<<<6272, blk, 0, stream>>>(G, g2, bb2, CI, Xb);
    gemm128<true, 0><<<dim3(24 * 49), blk, 0, stream>>>(
        Xb, BW + OFF_FC1, fc1_b, nullptr, nullptr, 0.f, nullptr, MB, 6272, 3072, 768,
        nullptr, nullptr);
    gemm_bt<true, 0><<<dim3(3 * 98), blk, 0, stream>>>(
        CI, ma_w1, ma_b1, nullptr, nullptr, 0.f, Hb, 6272, 192, 768, nullptr, nullptr);
    gemm_bt<false, 0><<<dim3(12 * 98), blk, 0, stream>>>(
        Hb, ma_w2, ma_b2, nullptr, nullptr, 0.f, F, 6272, 768, 192, nullptr, nullptr);
    gemm128x64<false, 0, 0><<<dim3(12 * 49), blk, 0, stream>>>(
        MB, BW + OFF_FC2, fc2_b, G, F, 0.5f, out_t, nullptr, 6272, 768, 3072,
        nullptr, nullptr, nullptr, nullptr, nullptr);
}

// Round 12
// 917.221 us; speedup vs baseline: 1.0162x; 1.0162x over previous
//
#include <hip/hip_runtime.h>
#include <hip/hip_bf16.h>
#include <math.h>

// ---------------------------------------------------------------------------
// Block_38543036514772 on MI355X (gfx950). f32 in/out; bf16 MFMA internals.
// R18: unbundle R17. KEEP flash T5 setprio + T13 defer-max (measured -5%:
// 105.3 -> 100us). REVERT the AF reg-staging fusions (addpos/t2s_prep_q in
// GEMM): they replaced 6 global_load_lds with 16 f32 loads + adds + 8
// ds_writes per thread/K-tile at 2x A-bytes, re-read 12x per M-row -> ~+20us
// across two GEMMs (R17 bundle arithmetic). Standalone elementwise kernels
// restored. GEMMs = R16 exactly (XCD swizzle kept, neutral).
// ---------------------------------------------------------------------------

typedef __bf16 bf16_t;
typedef bf16_t bf16x4 __attribute__((ext_vector_type(4)));
typedef bf16_t bf16x8 __attribute__((ext_vector_type(8)));
typedef float  f32x4  __attribute__((ext_vector_type(4)));

typedef const __attribute__((address_space(1))) void* gas_t;
typedef __attribute__((address_space(3))) void* las_t;
__device__ __forceinline__ void async16(const void* g, void* l) {
    // LDS dest = wave-uniform base + lane*16 (no padding allowed!)
    __builtin_amdgcn_global_load_lds((gas_t)g, (las_t)l, 16, 0, 0);
}

#define MFMA(a,b,c) __builtin_amdgcn_mfma_f32_16x16x32_bf16((a),(b),(c),0,0,0)
#define EXP2(x) __builtin_amdgcn_exp2f(x)
#define LOG2E 1.4426950408889634f

// Bijective XCD chunking (m204): physical bid -> logical id such that each
// XCD (bid%8) owns a contiguous logical chunk. Valid for any nwg.
__device__ __forceinline__ int xcd_swz(int bid, int nwg) {
    const int q = nwg >> 3, r = nwg & 7, x = bid & 7, o = bid >> 3;
    return (x < r ? x * (q + 1) : r * (q + 1) + (x - r) * q) + o;
}

// ---------------------------------------------------------------------------
// Big GEMM 128x128: Y = act(A[M,K]bf16 * W[N,K]bf16^T + bias) (+res1)(+s*res2)
// ---------------------------------------------------------------------------
template<bool GELU>
__global__ __launch_bounds__(256) void gemm128(
    const bf16_t* __restrict__ A, const bf16_t* __restrict__ W,
    const float* __restrict__ bias,
    const float* __restrict__ res1, const float* __restrict__ res2,
    float res2_scale,
    float* __restrict__ Yf, bf16_t* __restrict__ Yb,
    int M, int N, int K)
{
    __shared__ bf16_t As[128*64];
    __shared__ bf16_t Bs[128*64];
    const int tid = threadIdx.x, wave = tid >> 6, lane = tid & 63;
    const int nbx = N >> 7;
    const int lb = xcd_swz(blockIdx.x, gridDim.x);
    const int m0 = (lb / nbx) * 128, n0 = (lb % nbx) * 128;
    const int wm = (wave & 1) * 64, wn = (wave >> 1) * 64;
    const int l15 = lane & 15, lq = lane >> 4;
    const int lrow = lane >> 3, lcol = (lane & 7) * 8;

    f32x4 acc[4][4] = {};

    for (int k0 = 0; k0 < K; k0 += 64) {
#pragma unroll
        for (int c = 0; c < 4; ++c) {
            const int r = wave * 32 + c * 8;
            async16(A + (size_t)(m0 + r + lrow) * K + k0 + lcol, &As[r * 64]);
            async16(W + (size_t)(n0 + r + lrow) * K + k0 + lcol, &Bs[r * 64]);
        }
        __syncthreads();
#pragma unroll
        for (int kk = 0; kk < 64; kk += 32) {
            bf16x8 a[4], b[4];
#pragma unroll
            for (int i = 0; i < 4; ++i)
                a[i] = *(const bf16x8*)&As[(wm + i * 16 + l15) * 64 + kk + lq * 8];
#pragma unroll
            for (int i = 0; i < 4; ++i)
                b[i] = *(const bf16x8*)&Bs[(wn + i * 16 + l15) * 64 + kk + lq * 8];
#pragma unroll
            for (int mi = 0; mi < 4; ++mi)
#pragma unroll
                for (int ni = 0; ni < 4; ++ni)
                    acc[mi][ni] = MFMA(a[mi], b[ni], acc[mi][ni]);
        }
        __syncthreads();
    }

#pragma unroll
    for (int mi = 0; mi < 4; ++mi)
#pragma unroll
    for (int ni = 0; ni < 4; ++ni) {
        const int gn = n0 + wn + ni * 16 + l15;
        const float bv = bias ? bias[gn] : 0.f;
#pragma unroll
        for (int i = 0; i < 4; ++i) {
            const int gm = m0 + wm + mi * 16 + lq * 4 + i;
            float v = acc[mi][ni][i] + bv;
            if (GELU) v = 0.5f * v * (1.0f + erff(v * 0.70710678118654752f));
            const size_t off = (size_t)gm * N + gn;
            if (res1) v += res1[off];
            if (res2) v += res2_scale * res2[off];
            if (Yf) Yf[off] = v;
            if (Yb) Yb[off] = (bf16_t)v;
        }
    }
}

// ---------------------------------------------------------------------------
// GEMM 128x64 tile for N=768 layers. 1-D grid, XCD-swizzled.
// EPI=1: fused t2s_prep_kv write; EPI=2: fused s_out write.
// ---------------------------------------------------------------------------
template<bool GELU, int EPI>
__global__ __launch_bounds__(256) void gemm128x64(
    const bf16_t* __restrict__ A, const bf16_t* __restrict__ W,
    const float* __restrict__ bias,
    const float* __restrict__ res1, const float* __restrict__ res2,
    float res2_scale,
    float* __restrict__ Yf, bf16_t* __restrict__ Yb,
    int M, int N, int K,
    const float* __restrict__ ep_a, float* __restrict__ ep_fo,
    bf16_t* __restrict__ ep_bo)
{
    __shared__ bf16_t As[128*64];
    __shared__ bf16_t Bs[64*64];
    const int tid = threadIdx.x, wave = tid >> 6, lane = tid & 63;
    const int nbx = N >> 6;
    const int lb = xcd_swz(blockIdx.x, gridDim.x);
    const int m0 = (lb / nbx) * 128, n0 = (lb % nbx) * 64;
    const int wm = (wave & 1) * 64, wn = (wave >> 1) * 32;
    const int l15 = lane & 15, lq = lane >> 4;
    const int lrow = lane >> 3, lcol = (lane & 7) * 8;

    f32x4 acc[4][2] = {};

    for (int k0 = 0; k0 < K; k0 += 64) {
#pragma unroll
        for (int c = 0; c < 4; ++c) {
            const int r = wave * 32 + c * 8;
            async16(A + (size_t)(m0 + r + lrow) * K + k0 + lcol, &As[r * 64]);
        }
#pragma unroll
        for (int c = 0; c < 2; ++c) {
            const int r = wave * 16 + c * 8;
            async16(W + (size_t)(n0 + r + lrow) * K + k0 + lcol, &Bs[r * 64]);
        }
        __syncthreads();
#pragma unroll
        for (int kk = 0; kk < 64; kk += 32) {
            bf16x8 a[4], b[2];
#pragma unroll
            for (int i = 0; i < 4; ++i)
                a[i] = *(const bf16x8*)&As[(wm + i * 16 + l15) * 64 + kk + lq * 8];
#pragma unroll
            for (int i = 0; i < 2; ++i)
                b[i] = *(const bf16x8*)&Bs[(wn + i * 16 + l15) * 64 + kk + lq * 8];
#pragma unroll
            for (int mi = 0; mi < 4; ++mi)
#pragma unroll
                for (int ni = 0; ni < 2; ++ni)
                    acc[mi][ni] = MFMA(a[mi], b[ni], acc[mi][ni]);
        }
        __syncthreads();
    }

#pragma unroll
    for (int mi = 0; mi < 4; ++mi)
#pragma unroll
    for (int ni = 0; ni < 2; ++ni) {
        const int gn = n0 + wn + ni * 16 + l15;
        const float bv = bias ? bias[gn] : 0.f;
#pragma unroll
        for (int i = 0; i < 4; ++i) {
            const int gm = m0 + wm + mi * 16 + lq * 4 + i;
            float v = acc[mi][ni][i] + bv;
            if (GELU) v = 0.5f * v * (1.0f + erff(v * 0.70710678118654752f));
            const size_t off = (size_t)gm * N + gn;
            if (res1) v += res1[off];
            if (res2) v += res2_scale * res2[off];
            if (Yf) Yf[off] = v;
            if (Yb) Yb[off] = (bf16_t)v;
            if (EPI == 1) {
                // gm = b*1568 + t*196 + n  ->  dest = (b*196+n)*8 + t
                const int b_ = gm / 1568, r_ = gm - b_ * 1568;
                const int t_ = r_ / 196,  n_ = r_ - t_ * 196;
                const int dest = ((b_ * 196 + n_) << 3) + t_;
                ep_bo[(size_t)dest * 768 + gn] =
                    (bf16_t)(v + ep_a[t_ * 768 + gn]);
            }
            if (EPI == 2) {
                // gm = (b*196+n)*8 + t  ->  dest = (b*8+t)*196 + n
                const int t_ = gm & 7, bn_ = gm >> 3;
                const int n_ = bn_ % 196, b_ = bn_ / 196;
                const int dest = (b_ * 8 + t_) * 196 + n_;
                const size_t doff = (size_t)dest * 768 + gn;
                ep_fo[doff] = ep_a[doff] + v;
            }
        }
    }
}

// ---------------------------------------------------------------------------
// Small GEMM (adapters, N or K = 192): f32 in, 64x64 tile. 1-D swizzled grid.
// EPI=1: also write ep_bo[off] = bf16(v + ep_pos[(gm%196)*768 + gn])
// ---------------------------------------------------------------------------
template<bool GELU, int EPI>
__global__ __launch_bounds__(256) void gemm_bt(
    const float* __restrict__ X, const float* __restrict__ W,
    const float* __restrict__ bias,
    const float* __restrict__ res1, const float* __restrict__ res2,
    float res2_scale,
    float* __restrict__ Y, int M, int N, int K,
    const float* __restrict__ ep_pos, bf16_t* __restrict__ ep_bo)
{
    __shared__ bf16_t As[64][72];
    __shared__ bf16_t Bs[64][72];
    const int tid  = threadIdx.x;
    const int nbx  = N >> 6;
    const int lb   = xcd_swz(blockIdx.x, gridDim.x);
    const int n0   = (lb % nbx) * 64;
    const int m0   = (lb / nbx) * 64;
    const int wave = tid >> 6, lane = tid & 63;
    const int wm   = (wave & 1) * 32, wn = (wave >> 1) * 32;
    const int l15  = lane & 15, lq = lane >> 4;
    f32x4 acc[2][2] = {};
    const int sr = tid >> 4;
    const int sc4 = (tid & 15) * 4;

    for (int k0 = 0; k0 < K; k0 += 64) {
#pragma unroll
        for (int i = 0; i < 4; ++i) {
            const int row = sr + i * 16;
            const float4 xv = *reinterpret_cast<const float4*>(
                X + (size_t)(m0 + row) * K + k0 + sc4);
            bf16x4 p;
            p[0] = (bf16_t)xv.x; p[1] = (bf16_t)xv.y;
            p[2] = (bf16_t)xv.z; p[3] = (bf16_t)xv.w;
            *reinterpret_cast<bf16x4*>(&As[row][sc4]) = p;
        }
#pragma unroll
        for (int i = 0; i < 4; ++i) {
            const int row = sr + i * 16;
            const float4 wv = *reinterpret_cast<const float4*>(
                W + (size_t)(n0 + row) * K + k0 + sc4);
            bf16x4 p;
            p[0] = (bf16_t)wv.x; p[1] = (bf16_t)wv.y;
            p[2] = (bf16_t)wv.z; p[3] = (bf16_t)wv.w;
            *reinterpret_cast<bf16x4*>(&Bs[row][sc4]) = p;
        }
        __syncthreads();
#pragma unroll
        for (int kk = 0; kk < 64; kk += 32) {
            bf16x8 a0 = *reinterpret_cast<const bf16x8*>(&As[wm +      l15][kk + lq * 8]);
            bf16x8 a1 = *reinterpret_cast<const bf16x8*>(&As[wm + 16 + l15][kk + lq * 8]);
            bf16x8 b0 = *reinterpret_cast<const bf16x8*>(&Bs[wn +      l15][kk + lq * 8]);
            bf16x8 b1 = *reinterpret_cast<const bf16x8*>(&Bs[wn + 16 + l15][kk + lq * 8]);
            acc[0][0] = MFMA(a0, b0, acc[0][0]);
            acc[0][1] = MFMA(a0, b1, acc[0][1]);
            acc[1][0] = MFMA(a1, b0, acc[1][0]);
            acc[1][1] = MFMA(a1, b1, acc[1][1]);
        }
        __syncthreads();
    }

#pragma unroll
    for (int mt = 0; mt < 2; ++mt)
#pragma unroll
    for (int nt = 0; nt < 2; ++nt) {
        const int gn = n0 + wn + nt * 16 + l15;
        const float bv = bias[gn];
#pragma unroll
        for (int i = 0; i < 4; ++i) {
            const int gm = m0 + wm + mt * 16 + lq * 4 + i;
            float v = acc[mt][nt][i] + bv;
            if (GELU) v = 0.5f * v * (1.0f + erff(v * 0.70710678118654752f));
            const size_t off = (size_t)gm * N + gn;
            if (res1) v += res1[off];
            if (res2) v += res2_scale * res2[off];
            Y[off] = v;
            if (EPI == 1) {
                const int n_ = gm % 196;
                ep_bo[off] = (bf16_t)(v + ep_pos[n_ * 768 + gn]);
            }
        }
    }
}

// ---------------------------------------------------------------------------
// Flash attention v9 (swapped QK^T): wave w owns Q rows [16w,16w+16).
// Q frags in REGISTERS. K staged row-major coalesced; V staged via row-loads
// + scalar transpose ds_writes. P^T packed b64 into own Ps buffer -> 2
// barriers/iter. setprio(1) around QK/PV MFMA clusters (T5) + defer-max
// rescale (T13, THR=8 exp2-domain, wave-uniform branch).
// ---------------------------------------------------------------------------
__global__ __launch_bounds__(256) void flash_k(
    const bf16_t* __restrict__ Q, int ldq,
    const bf16_t* __restrict__ Kp, int ldk,
    const bf16_t* __restrict__ Vp, int ldv,
    bf16_t* __restrict__ O, int ldo,
    int nq, int nk, float scale)
{
    __shared__ bf16_t Ks[64 * 68];
    __shared__ bf16_t Vs[64 * 68];    // V^T: [dim][key]
    __shared__ bf16_t Ps[64 * 68];    // P: [q-row][key], wave-private rows

    const int tid = threadIdx.x, wave = tid >> 6, lane = tid & 63;
    const int q0 = blockIdx.x * 64, hoff = blockIdx.y * 64, g = blockIdx.z;
    const int l15 = lane & 15, lq = lane >> 4;
    const int wm16 = wave * 16;
    const int sr = tid >> 3, sc8 = (tid & 7) * 8;   // K staging: 32 rows x 8 chunks
    const float sl2e = scale * LOG2E;

    // ---- Q fragments in registers (loop-invariant) ----
    bf16x8 bq0, bq1;
    {
        int qr = q0 + wm16 + l15; if (qr > nq - 1) qr = nq - 1;
        const bf16_t* qp = Q + ((size_t)g * nq + qr) * ldq + hoff + lq * 8;
        bq0 = *(const bf16x8*)qp;
        bq1 = *(const bf16x8*)(qp + 32);
    }

    // ---- prologue: prefetch K/V tile 0 into regs (coalesced row loads) ----
    bf16x8 ka, kb, va, vb;
    {
        int r0 = sr;      if (r0 > nk - 1) r0 = nk - 1;
        int r1 = sr + 32; if (r1 > nk - 1) r1 = nk - 1;
        ka = *(const bf16x8*)(Kp + ((size_t)g * nk + r0) * ldk + hoff + sc8);
        kb = *(const bf16x8*)(Kp + ((size_t)g * nk + r1) * ldk + hoff + sc8);
        int key = lane; if (key > nk - 1) key = nk - 1;
        const bf16_t* vp = Vp + ((size_t)g * nk + key) * ldv + hoff + wm16;
        va = *(const bf16x8*)vp;
        vb = *(const bf16x8*)(vp + 8);
    }

    float m_r = -INFINITY, l_r = 0.f;   // softmax state for q-row = wm16 + l15
    f32x4 acc[4] = {};                  // O rows lq*4+i, cols nt*16+l15

    for (int kk0 = 0; kk0 < nk; kk0 += 64) {
        __syncthreads();   // prev-iter QK/PV reads of Ks/Vs done; prefetch ready
        // ---- regs -> LDS (K rows; V transposed via scalar stores) ----
        *(bf16x8*)&Ks[sr * 68 + sc8] = ka;
        *(bf16x8*)&Ks[(sr + 32) * 68 + sc8] = kb;
#pragma unroll
        for (int j = 0; j < 8; ++j) Vs[(wm16 + j) * 68 + lane] = va[j];
#pragma unroll
        for (int j = 0; j < 8; ++j) Vs[(wm16 + 8 + j) * 68 + lane] = vb[j];
        __syncthreads();   // staging visible

        // ---- issue NEXT tile's global loads (fly under compute) ----
        const int nx = kk0 + 64;
        if (nx < nk) {
            int r0 = nx + sr;      if (r0 > nk - 1) r0 = nk - 1;
            int r1 = nx + sr + 32; if (r1 > nk - 1) r1 = nk - 1;
            ka = *(const bf16x8*)(Kp + ((size_t)g * nk + r0) * ldk + hoff + sc8);
            kb = *(const bf16x8*)(Kp + ((size_t)g * nk + r1) * ldk + hoff + sc8);
            int key = nx + lane; if (key > nk - 1) key = nk - 1;
            const bf16_t* vp = Vp + ((size_t)g * nk + key) * ldv + hoff + wm16;
            va = *(const bf16x8*)vp;
            vb = *(const bf16x8*)(vp + 8);
        }

        // ---- S^T = K Q^T : s[nt] = S[k=kk0+nt*16+lq*4+i][q=wm16+l15] ----
        f32x4 s[4] = {};
        __builtin_amdgcn_s_setprio(1);
#pragma unroll
        for (int nt = 0; nt < 4; ++nt) {
            bf16x8 ak0 = *(const bf16x8*)&Ks[(nt * 16 + l15) * 68 + lq * 8];
            bf16x8 ak1 = *(const bf16x8*)&Ks[(nt * 16 + l15) * 68 + 32 + lq * 8];
            s[nt] = MFMA(ak0, bq0, s[nt]);
            s[nt] = MFMA(ak1, bq1, s[nt]);
        }
        __builtin_amdgcn_s_setprio(0);

        // ---- mask + scale (k index is lane-local) ----
#pragma unroll
        for (int nt = 0; nt < 4; ++nt)
#pragma unroll
        for (int i = 0; i < 4; ++i) {
            const bool valid = (kk0 + nt * 16 + lq * 4 + i) < nk;
            s[nt][i] = valid ? s[nt][i] * sl2e : -INFINITY;
        }

        // ---- row softmax: local 16-tree + 2 shfl; defer-max (THR=8) ----
        float t0 = fmaxf(fmaxf(s[0][0], s[0][1]), fmaxf(s[0][2], s[0][3]));
        float t1 = fmaxf(fmaxf(s[1][0], s[1][1]), fmaxf(s[1][2], s[1][3]));
        float t2 = fmaxf(fmaxf(s[2][0], s[2][1]), fmaxf(s[2][2], s[2][3]));
        float t3 = fmaxf(fmaxf(s[3][0], s[3][1]), fmaxf(s[3][2], s[3][3]));
        float t = fmaxf(fmaxf(t0, t1), fmaxf(t2, t3));
        t = fmaxf(t, __shfl_xor(t, 16));
        t = fmaxf(t, __shfl_xor(t, 32));
        if (!__all(t <= m_r + 8.f)) {          // rescale path (always at iter 0)
            const float mnew = fmaxf(m_r, t);  // finite: >=1 valid k per tile
            const float a = EXP2(m_r - mnew);
            float alq[4];
#pragma unroll
            for (int i = 0; i < 4; ++i) alq[i] = __shfl(a, lq * 4 + i);
            l_r *= a;
#pragma unroll
            for (int nt = 0; nt < 4; ++nt)
#pragma unroll
            for (int i = 0; i < 4; ++i)
                acc[nt][i] *= alq[i];
            m_r = mnew;
        }
        float ps = 0.f;
#pragma unroll
        for (int nt = 0; nt < 4; ++nt)
#pragma unroll
        for (int i = 0; i < 4; ++i) {
            const float e = EXP2(s[nt][i] - m_r);  // -inf -> 0; bounded by 2^8
            s[nt][i] = e; ps += e;
        }
        ps += __shfl_xor(ps, 16);
        ps += __shfl_xor(ps, 32);
        l_r += ps;

        // ---- P^T into Ps, packed b64 (own rows; same-wave order = safe) ----
#pragma unroll
        for (int nt = 0; nt < 4; ++nt) {
            bf16x4 pk;
            pk[0] = (bf16_t)s[nt][0]; pk[1] = (bf16_t)s[nt][1];
            pk[2] = (bf16_t)s[nt][2]; pk[3] = (bf16_t)s[nt][3];
            *(bf16x4*)&Ps[(wm16 + l15) * 68 + nt * 16 + lq * 4] = pk;
        }

        // ---- O += P*V ----
        __builtin_amdgcn_s_setprio(1);
#pragma unroll
        for (int kk = 0; kk < 64; kk += 32) {
            bf16x8 ap = *(const bf16x8*)&Ps[(wm16 + l15) * 68 + kk + lq * 8];
#pragma unroll
            for (int nt = 0; nt < 4; ++nt) {
                bf16x8 bv = *(const bf16x8*)&Vs[(nt * 16 + l15) * 68 + kk + lq * 8];
                acc[nt] = MFMA(ap, bv, acc[nt]);
            }
        }
        __builtin_amdgcn_s_setprio(0);
    }

    // ---- epilogue: 1/l gathered to acc rows ----
    float linv[4];
#pragma unroll
    for (int i = 0; i < 4; ++i)
        linv[i] = __builtin_amdgcn_rcpf(__shfl(l_r, lq * 4 + i));
#pragma unroll
    for (int nt = 0; nt < 4; ++nt)
#pragma unroll
    for (int i = 0; i < 4; ++i) {
        const int qrow = q0 + wm16 + lq * 4 + i;
        if (qrow < nq)
            O[((size_t)g * nq + qrow) * ldo + hoff + nt * 16 + l15] =
                (bf16_t)(acc[nt][i] * linv[i]);
    }
}

// ---------------------------------------------------------------------------
// T2S attention (nq=nk=8, D=64, 12 heads): ONE WAVE per (seq, head).
// ---------------------------------------------------------------------------
__global__ __launch_bounds__(256) void attn8_k(
    const bf16_t* __restrict__ Q, int ldq,
    const bf16_t* __restrict__ Kp, int ldk,
    const bf16_t* __restrict__ Vp, int ldv,
    bf16_t* __restrict__ O, int ldo,
    float scale)
{
    __shared__ float Ps[4][8][8];
    const int wv = threadIdx.x >> 6, lane = threadIdx.x & 63;
    const int gw  = blockIdx.x * 4 + wv;       // global wave id in [0, 9408)
    const int seq = gw / 12, h = gw - seq * 12;
    const int hoff = h * 64;
    const int l15 = lane & 15, lq = lane >> 4;
    const size_t rbase = (size_t)seq * 8;
    const float sl2e = scale * LOG2E;

    // ---- S = Q K^T : one 16x16 tile (8x8 valid) ----
    const int qr = l15 & 7;                     // rows/cols 8..15 duplicate 0..7
    const bf16_t* qp = Q  + (rbase + qr) * ldq + hoff + lq * 8;
    const bf16_t* kp = Kp + (rbase + qr) * ldk + hoff + lq * 8;
    bf16x8 a0 = *(const bf16x8*)qp;
    bf16x8 a1 = *(const bf16x8*)(qp + 32);
    bf16x8 b0 = *(const bf16x8*)kp;
    bf16x8 b1 = *(const bf16x8*)(kp + 32);
    f32x4 z = {};
    f32x4 s = MFMA(a1, b1, MFMA(a0, b0, z));
    // C layout: col(key) = l15, row(query) = lq*4+i — rows valid iff lq<2.

    // ---- softmax over 8 keys per row (cols 8..15 masked) ----
    const bool cvalid = l15 < 8;
    float p[4];
#pragma unroll
    for (int i = 0; i < 4; ++i) {
        float v = cvalid ? s[i] * sl2e : -INFINITY;
        float m = v;
        m = fmaxf(m, __shfl_xor(m, 1));
        m = fmaxf(m, __shfl_xor(m, 2));
        m = fmaxf(m, __shfl_xor(m, 4));
        m = fmaxf(m, __shfl_xor(m, 8));
        float e = EXP2(v - m);                  // -inf -> 0
        float sum = e;
        sum += __shfl_xor(sum, 1);
        sum += __shfl_xor(sum, 2);
        sum += __shfl_xor(sum, 4);
        sum += __shfl_xor(sum, 8);
        p[i] = e * __builtin_amdgcn_rcpf(sum);  // sum >= 1 (row max contributes 1)
    }
    if (lq < 2 && cvalid) {
#pragma unroll
        for (int i = 0; i < 4; ++i)
            Ps[wv][lq * 4 + i][l15] = p[i];
    }
    __syncthreads();

    // ---- O[qi][dg*8..+8) = sum_k P[qi][k] * V[k][...] ----
    const int qi = lane >> 3, dg = lane & 7;
    f32x4 p0 = *(const f32x4*)&Ps[wv][qi][0];
    f32x4 p1 = *(const f32x4*)&Ps[wv][qi][4];
    float acc[8] = {};
#pragma unroll
    for (int k = 0; k < 8; ++k) {
        const bf16x8 vvec = *(const bf16x8*)(Vp + (rbase + k) * ldv + hoff + dg * 8);
        const float pk = (k < 4) ? p0[k] : p1[k - 4];
#pragma unroll
        for (int j = 0; j < 8; ++j) acc[j] += pk * (float)vvec[j];
    }
    bf16x8 o;
#pragma unroll
    for (int j = 0; j < 8; ++j) o[j] = (bf16_t)acc[j];
    *(bf16x8*)(O + (rbase + qi) * ldo + hoff + dg * 8) = o;
}

// ---------------------------------------------------------------------------
// LayerNorm(768): bf16 out always, f32 out optional. Shfl reduce, 1 barrier.
// ---------------------------------------------------------------------------
__global__ __launch_bounds__(256) void ln_k(
    const float* __restrict__ x,
    const float* __restrict__ g, const float* __restrict__ bta,
    float* __restrict__ yf, bf16_t* __restrict__ yb)
{
    __shared__ float rA[4], rB[4];
    const int row = blockIdx.x, tid = threadIdx.x;
    const int wv = tid >> 6, lane = tid & 63;
    const size_t base = (size_t)row * 768;
    const float v0 = x[base + tid];
    const float v1 = x[base + tid + 256];
    const float v2 = x[base + tid + 512];
    float s1 = v0 + v1 + v2;
    float s2 = v0 * v0 + v1 * v1 + v2 * v2;
#pragma unroll
    for (int off = 32; off > 0; off >>= 1) {
        s1 += __shfl_xor(s1, off);
        s2 += __shfl_xor(s2, off);
    }
    if (lane == 0) { rA[wv] = s1; rB[wv] = s2; }
    __syncthreads();
    const float ts1 = rA[0] + rA[1] + rA[2] + rA[3];
    const float ts2 = rB[0] + rB[1] + rB[2] + rB[3];
    const float m = ts1 * (1.f / 768.f);
    const float r = rsqrtf(ts2 * (1.f / 768.f) - m * m + 1e-5f);
    const float o0 = (v0 - m) * r * g[tid]       + bta[tid];
    const float o1 = (v1 - m) * r * g[tid + 256] + bta[tid + 256];
    const float o2 = (v2 - m) * r * g[tid + 512] + bta[tid + 512];
    yb[base + tid]       = (bf16_t)o0;
    yb[base + tid + 256] = (bf16_t)o1;
    yb[base + tid + 512] = (bf16_t)o2;
    if (yf) {
        yf[base + tid]       = o0;
        yf[base + tid + 256] = o1;
        yf[base + tid + 512] = o2;
    }
}

// --------------------------- elementwise helpers ---------------------------
__global__ void addpos_k(const float* __restrict__ src, const float* __restrict__ pos,
                         bf16_t* __restrict__ dst, int nrep) {
    const int row = blockIdx.x, tid = threadIdx.x;
    const size_t base = (size_t)row * 768;
    const size_t pbase = (size_t)(row % nrep) * 768;
    for (int k = 0; k < 3; ++k) {
        int c = tid + k * 256;
        dst[base + c] = (bf16_t)(src[base + c] + pos[pbase + c]);
    }
}
__global__ void t2s_prep_q(const float* __restrict__ sx, const float* __restrict__ pos,
                           bf16_t* __restrict__ dst) {
    const int row = blockIdx.x, tid = threadIdx.x;
    const int t = row & 7, bn = row >> 3, n = bn % 196, b = bn / 196;
    const size_t src = (size_t)((b * 8 + t) * 196 + n) * 768;
    const size_t dbase = (size_t)row * 768;
    const size_t pbase = (size_t)t * 768;
    for (int k = 0; k < 3; ++k) {
        int c = tid + k * 256;
        dst[dbase + c] = (bf16_t)(sx[src + c] + pos[pbase + c]);
    }
}
__global__ void build_qkv_bias(const float* __restrict__ qb,
                               const float* __restrict__ vb,
                               float* __restrict__ dst) {
    int i = blockIdx.x * 256 + threadIdx.x;
    if (i < 768) dst[i] = qb[i];
    else if (i < 1536) dst[i] = 0.f;
    else if (i < 2304) dst[i] = vb[i - 1536];
}

// Weight convert: 10 f32 weights -> one bf16 arena (float4 granularity).
// cum[i] = OFF_i / 4.
struct WPtrs { const float* p[10]; };
__global__ void wcvt(WPtrs s, bf16_t* __restrict__ dst) {
    const int cum[11] = {0, 442368, 589824, 737280, 1032192, 1179648,
                         1327104, 1622016, 1769472, 2359296, 2949120};
    const int gi = blockIdx.x * 256 + threadIdx.x;
    int seg = 0;
#pragma unroll
    for (int i = 1; i < 10; ++i) if (gi >= cum[i]) seg = i;
    const float4 v = ((const float4*)s.p[seg])[gi - cum[seg]];
    bf16x4 o;
    o[0] = (bf16_t)v.x; o[1] = (bf16_t)v.y; o[2] = (bf16_t)v.z; o[3] = (bf16_t)v.w;
    ((bf16x4*)dst)[gi] = o;
}

// Arena offsets (elements)
#define OFF_QKV    0
#define OFF_APROJ  1769472
#define OFF_S2TQ   2359296
#define OFF_S2TKV  2949120
#define OFF_S2TP   4128768
#define OFF_T2SQ   4718592
#define OFF_T2SKV  5308416
#define OFF_T2SP   6488064
#define OFF_FC1    7077888
#define OFF_FC2    9437184
#define W_TOTAL    11796480

// ---------------------------------------------------------------------------
extern "C" void kernel_launch(void* const* d_in, const int* in_sizes, int n_in,
                              void* d_out, int out_size, void* d_ws, size_t ws_size,
                              hipStream_t stream)
{
    typedef const float* fp;
    fp s_x     = (fp)d_in[0];
    fp t_x     = (fp)d_in[1];
    fp g1      = (fp)d_in[2];
    fp bb1     = (fp)d_in[3];
    fp qkv_w   = (fp)d_in[4];
    fp q_bias  = (fp)d_in[5];
    fp v_bias  = (fp)d_in[6];
    fp aproj_w = (fp)d_in[7];
    fp aproj_b = (fp)d_in[8];
    fp sa_w1   = (fp)d_in[9];
    fp sa_b1   = (fp)d_in[10];
    fp sa_w2   = (fp)d_in[11];
    fp sa_b2   = (fp)d_in[12];
    fp s2t_pos_cnn  = (fp)d_in[13];
    fp s2t_pos_vmae = (fp)d_in[14];
    fp s2t_qw  = (fp)d_in[15];
    fp s2t_qb  = (fp)d_in[16];
    fp s2t_kvw = (fp)d_in[17];
    fp s2t_kvb = (fp)d_in[18];
    fp s2t_pw  = (fp)d_in[19];
    fp s2t_pb  = (fp)d_in[20];
    fp t2s_pos_cnn  = (fp)d_in[21];
    fp t2s_pos_vmae = (fp)d_in[22];
    fp t2s_qw  = (fp)d_in[23];
    fp t2s_qb  = (fp)d_in[24];
    fp t2s_kvw = (fp)d_in[25];
    fp t2s_kvb = (fp)d_in[26];
    fp t2s_pw  = (fp)d_in[27];
    fp t2s_pb  = (fp)d_in[28];
    fp g2      = (fp)d_in[29];
    fp bb2     = (fp)d_in[30];
    fp fc1_w   = (fp)d_in[31];
    fp fc1_b   = (fp)d_in[32];
    fp fc2_w   = (fp)d_in[33];
    fp fc2_b   = (fp)d_in[34];
    fp ma_w1   = (fp)d_in[35];
    fp ma_b1   = (fp)d_in[36];
    fp ma_w2   = (fp)d_in[37];
    fp ma_b2   = (fp)d_in[38];

    const size_t RD = (size_t)6272 * 768;

    float* ws   = (float*)d_ws;
    float* F    = ws;                      // aproj out / mad out
    float* G    = F + RD;                  // running t
    float* CI   = G + RD;                  // ln2 f32 out (stage 4 only)
    float* Hb   = CI + RD;                 // 6272x192 adapter hidden
    float* qkvb = Hb + (size_t)6272 * 192;
    bf16_t* BW  = (bf16_t*)(qkvb + 2304);  // weight arena
    bf16_t* Xb  = BW + W_TOTAL;            // GEMM A-input staging (RD)
    bf16_t* Eb  = Xb + RD;                 // q mirrors / flash out (RD)
    bf16_t* Fb  = Eb + RD;                 // flash/attn out (RD)
    bf16_t* MB  = Fb + RD;                 // big mirror: qkv/kv/fc1 (6272x3072)
    bf16_t* Xkv = MB + (size_t)6272 * 1536; // fused t2s-kv staging (MB 2nd half)

    float* out_s = (float*)d_out;          // [32*196, 768]
    float* out_t = out_s + RD;             // [4*1568, 768]

    const dim3 blk(256);

    // ---- weight conversion ----
    WPtrs wp;
    wp.p[0] = qkv_w;  wp.p[1] = aproj_w; wp.p[2] = s2t_qw; wp.p[3] = s2t_kvw;
    wp.p[4] = s2t_pw; wp.p[5] = t2s_qw;  wp.p[6] = t2s_kvw; wp.p[7] = t2s_pw;
    wp.p[8] = fc1_w;  wp.p[9] = fc2_w;
    wcvt<<<11520, blk, 0, stream>>>(wp, BW);

    // ---- stage 1: self-attention + serial adapter ----
    ln_k<<<6272, blk, 0, stream>>>(t_x, g1, bb1, nullptr, Xb);
    build_qkv_bias<<<9, blk, 0, stream>>>(q_bias, v_bias, qkvb);
    gemm128<false><<<dim3(18 * 49), blk, 0, stream>>>(
        Xb, BW + OFF_QKV, qkvb, nullptr, nullptr, 0.f, nullptr, MB, 6272, 2304, 768);
    flash_k<<<dim3(25, 12, 4), blk, 0, stream>>>(
        MB, 2304, MB + 768, 2304, MB + 1536, 2304, Eb, 768, 1568, 1568, 0.125f);
    gemm128x64<false, 0><<<dim3(12 * 49), blk, 0, stream>>>(
        Eb, BW + OFF_APROJ, aproj_b, nullptr, nullptr, 0.f, F, nullptr, 6272, 768, 768,
        nullptr, nullptr, nullptr);
    gemm_bt<true, 0><<<dim3(3 * 98), blk, 0, stream>>>(
        F, sa_w1, sa_b1, nullptr, nullptr, 0.f, Hb, 6272, 192, 768, nullptr, nullptr);
    // t1 = G; fused: Xb = bf16(t1 + s2t_pos_vmae[n])
    gemm_bt<false, 1><<<dim3(12 * 98), blk, 0, stream>>>(
        Hb, sa_w2, sa_b2, F, t_x, 1.0f, G, 6272, 768, 192, s2t_pos_vmae, Xb);

    // ---- stage 2: S2T cross-attn ----
    gemm128x64<false, 0><<<dim3(12 * 49), blk, 0, stream>>>(
        Xb, BW + OFF_S2TQ, s2t_qb, nullptr, nullptr, 0.f, nullptr, Eb, 6272, 768, 768,
        nullptr, nullptr, nullptr);
    addpos_k<<<6272, blk, 0, stream>>>(s_x, s2t_pos_cnn, Xb, 196);
    gemm128<false><<<dim3(12 * 49), blk, 0, stream>>>(
        Xb, BW + OFF_S2TKV, s2t_kvb, nullptr, nullptr, 0.f, nullptr, MB, 6272, 1536, 768);
    flash_k<<<dim3(4, 12, 32), blk, 0, stream>>>(
        Eb, 768, MB, 1536, MB + 768, 1536, Fb, 768, 196, 196, 0.125f);
    // t2 = G; fused: Xkv[perm] = bf16(t2 + t2s_pos_vmae[t])
    gemm128x64<false, 1><<<dim3(12 * 49), blk, 0, stream>>>(
        Fb, BW + OFF_S2TP, s2t_pb, G, nullptr, 0.f, G, nullptr, 6272, 768, 768,
        t2s_pos_vmae, nullptr, Xkv);

    // ---- stage 3: T2S cross-attn ----
    t2s_prep_q<<<6272, blk, 0, stream>>>(s_x, t2s_pos_cnn, Xb);
    gemm128x64<false, 0><<<dim3(12 * 49), blk, 0, stream>>>(
        Xb, BW + OFF_T2SQ, t2s_qb, nullptr, nullptr, 0.f, nullptr, Eb, 6272, 768, 768,
        nullptr, nullptr, nullptr);
    gemm128<false><<<dim3(12 * 49), blk, 0, stream>>>(
        Xkv, BW + OFF_T2SKV, t2s_kvb, nullptr, nullptr, 0.f, nullptr, MB, 6272, 1536, 768);
    attn8_k<<<dim3(2352), blk, 0, stream>>>(
        Eb, 768, MB, 1536, MB + 768, 1536, Fb, 768, 0.125f);
    // fused s_out: out_s[perm] = s_x[perm] + t2s_p(Fb)
    gemm128x64<false, 2><<<dim3(12 * 49), blk, 0, stream>>>(
        Fb, BW + OFF_T2SP, t2s_pb, nullptr, nullptr, 0.f, nullptr, nullptr,
        6272, 768, 768, s_x, out_s, nullptr);

    // ---- stage 4: MLP + parallel adapter ----
    ln_k<<<6272, blk, 0, stream>>>(G, g2, bb2, CI, Xb);
    gemm128<true><<<dim3(24 * 49), blk, 0, stream>>>(
        Xb, BW + OFF_FC1, fc1_b, nullptr, nullptr, 0.f, nullptr, MB, 6272, 3072, 768);
    gemm_bt<true, 0><<<dim3(3 * 98), blk, 0, stream>>>(
        CI, ma_w1, ma_b1, nullptr, nullptr, 0.f, Hb, 6272, 192, 768, nullptr, nullptr);
    gemm_bt<false, 0><<<dim3(12 * 98), blk, 0, stream>>>(
        Hb, ma_w2, ma_b2, nullptr, nullptr, 0.f, F, 6272, 768, 192, nullptr, nullptr);
    gemm128x64<false, 0><<<dim3(12 * 49), blk, 0, stream>>>(
        MB, BW + OFF_FC2, fc2_b, G, F, 0.5f, out_t, nullptr, 6272, 768, 3072,
        nullptr, nullptr, nullptr);
}